// Round 4
// baseline (524.452 us; speedup 1.0000x reference)
//
#include <hip/hip_runtime.h>
#include <math.h>

#define VSZ 50257
#define HSZ 1024
#define LSZ 2048
#define SHIFT 60.0f
#define NGEMM 128          // copy-GEMM blocks in k_huge
#define NGEMV 6283         // ceil(VSZ/8)

typedef __attribute__((ext_vector_type(8))) short bf16x8;
typedef __attribute__((ext_vector_type(4))) float f32x4;

__device__ __forceinline__ unsigned short f2bf(float f) {
  unsigned int u = __float_as_uint(f);
  u += 0x7FFFu + ((u >> 16) & 1u);  // RNE
  return (unsigned short)(u >> 16);
}

__device__ __forceinline__ float dot256(const float4* __restrict__ row,
                                        const float4* __restrict__ x, int lane) {
  float s = 0.f;
#pragma unroll
  for (int j = 0; j < 4; ++j) {
    float4 a = row[lane + 64 * j];
    float4 b = x[lane + 64 * j];
    s += a.x * b.x + a.y * b.y + a.z * b.z + a.w * b.w;
  }
  return s;
}

// ============ K1: everything that depends only on inputs ============
// 0..511: attnw GEMV. 512..1279: gh GEMV. 1280..1535: part = Wau[:,:H]@emb0+bau.
// 1536..1732: zero out[0..V). 1733..2500: fp32->bf16 conversion. 2501: zero psum.
__global__ void k_pre(const float* __restrict__ Waw, const float* __restrict__ baw,
                      const int* __restrict__ din, const float* __restrict__ emb,
                      const float* __restrict__ h0, const float* __restrict__ enc,
                      const float* __restrict__ Wc, const float* __restrict__ Whh,
                      const float* __restrict__ bhh, const float* __restrict__ Wau,
                      const float* __restrict__ bau, float* __restrict__ attnw,
                      float* __restrict__ gh, float* __restrict__ part,
                      float* __restrict__ out, float* __restrict__ psum,
                      unsigned short* __restrict__ bfbuf) {
  int bid = blockIdx.x, tid = threadIdx.x;
  int wave = tid >> 6, lane = tid & 63;
  if (bid < 512) {
    int gw = bid * 4 + wave;
    const float4* row = (const float4*)(Waw + (size_t)gw * 2048);
    float s = dot256(row, (const float4*)(emb + (size_t)din[0] * HSZ), lane)
            + dot256(row + 256, (const float4*)h0, lane);
#pragma unroll
    for (int o = 32; o > 0; o >>= 1) s += __shfl_down(s, o, 64);
    if (lane == 0) attnw[gw] = s + baw[gw];
  } else if (bid < 1280) {
    int gw = (bid - 512) * 4 + wave;  // < 3072
    float s = dot256((const float4*)(Whh + (size_t)gw * HSZ), (const float4*)h0, lane);
#pragma unroll
    for (int o = 32; o > 0; o >>= 1) s += __shfl_down(s, o, 64);
    if (lane == 0) gh[gw] = s + bhh[gw];
  } else if (bid < 1536) {
    int gw = (bid - 1280) * 4 + wave;  // < 1024
    float s = dot256((const float4*)(Wau + (size_t)gw * 2048),
                     (const float4*)(emb + (size_t)din[0] * HSZ), lane);
#pragma unroll
    for (int o = 32; o > 0; o >>= 1) s += __shfl_down(s, o, 64);
    if (lane == 0) part[gw] = s + bau[gw];
  } else if (bid < 1733) {
    int v = (bid - 1536) * 256 + tid;
    if (v < VSZ) out[v] = 0.f;
  } else if (bid < 2501) {
    int cb = bid - 1733;
#pragma unroll
    for (int c = 0; c < 4; ++c) {
      int g = cb * 1024 + c * 256 + tid;
      float4 v;
      if (g < 524288) v = ((const float4*)enc)[g];
      else            v = ((const float4*)Wc)[g - 524288];
      ushort4 o;
      o.x = f2bf(v.x); o.y = f2bf(v.y); o.z = f2bf(v.z); o.w = f2bf(v.w);
      *(ushort4*)(bfbuf + (size_t)g * 4) = o;
    }
  } else {
#pragma unroll
    for (int k = 0; k < 8; ++k) psum[tid + 256 * k] = 0.f;
  }
}

// ============ K2: in-block softmax(attnw) + attn_applied accumulate ============
__global__ void k_attn_apply(const float* __restrict__ attnw, const float* __restrict__ enc,
                             float* __restrict__ acc) {
  __shared__ float red[256];
  __shared__ float sw[64];
  int bid = blockIdx.x, t = threadIdx.x;
  int hb = bid & 3, mb = bid >> 2;
  float m = -1e30f;
  for (int i = t; i < LSZ; i += 256) m = fmaxf(m, attnw[i]);
  red[t] = m; __syncthreads();
  for (int s = 128; s > 0; s >>= 1) { if (t < s) red[t] = fmaxf(red[t], red[t + s]); __syncthreads(); }
  float gmax = red[0]; __syncthreads();
  float sum = 0.f;
  for (int i = t; i < LSZ; i += 256) sum += expf(attnw[i] - gmax);
  red[t] = sum; __syncthreads();
  for (int s = 128; s > 0; s >>= 1) { if (t < s) red[t] += red[t + s]; __syncthreads(); }
  float inv = 1.f / red[0];
  if (t < 64) sw[t] = expf(attnw[mb * 64 + t] - gmax) * inv;
  __syncthreads();
  int h = hb * 256 + t;
  float s = 0.f;
#pragma unroll 4
  for (int j = 0; j < 64; ++j) s = fmaf(sw[j], enc[(size_t)(mb * 64 + j) * HSZ + h], s);
  if (mb == 0) acc[h] = s;                 // block 0..3 seed
  else atomicAdd(&acc[h], s);
}

// ============ K3: rnn_in = relu(part + Wau[:,H:]@acc) ============
__global__ void k_rnn2(const float* __restrict__ Wau, const float* __restrict__ part,
                       const float* __restrict__ acc, float* __restrict__ rnn_in) {
  int gw = blockIdx.x * 4 + (threadIdx.x >> 6);
  int lane = threadIdx.x & 63;
  float s = dot256((const float4*)(Wau + (size_t)gw * 2048) + 256, (const float4*)acc, lane);
#pragma unroll
  for (int o = 32; o > 0; o >>= 1) s += __shfl_down(s, o, 64);
  if (lane == 0) rnn_in[gw] = fmaxf(s + part[gw], 0.f);
}

// ============ K4: gi = Wih @ rnn_in + bih ============
__global__ void k_gi(const float* __restrict__ Wih, const float* __restrict__ bih,
                     const float* __restrict__ rnn_in, float* __restrict__ gi) {
  int gw = blockIdx.x * 4 + (threadIdx.x >> 6);
  int lane = threadIdx.x & 63;
  float s = dot256((const float4*)(Wih + (size_t)gw * HSZ), (const float4*)rnn_in, lane);
#pragma unroll
  for (int o = 32; o > 0; o >>= 1) s += __shfl_down(s, o, 64);
  if (lane == 0) gi[gw] = s + bih[gw];
}

// ============ K5: fused copy-GEMM (bf16 MFMA) + GRU + vocab GEMV + exp-sums ============
// blocks 0..127: GEMM, block b = 16 l-rows x all 1024 h; waves split h into 256-chunks;
//                LDS cross-wave reduce -> final score_c (plain store) + exp contribution.
// blocks 128..: GEMV 8 rows/block; inline GRU recompute of h_new into LDS;
//               block 128 also writes out[V..V+H) and zeroes final_weights.
__global__ __launch_bounds__(256) void k_huge(
    const unsigned short* __restrict__ encB, const unsigned short* __restrict__ WcB,
    const float* __restrict__ bc, const float* __restrict__ hvec,
    const float* __restrict__ Wg, const float* __restrict__ bg,
    const float* __restrict__ gi, const float* __restrict__ gh,
    const float* __restrict__ h0, float* __restrict__ score,
    float* __restrict__ psum, float* __restrict__ out) {
  int bid = blockIdx.x, tid = threadIdx.x;
  int wave = tid >> 6, lane = tid & 63;
  if (bid < NGEMM) {
    __shared__ float sred[4][16];
    int l0 = bid * 16;
    int col = lane & 15, quad = lane >> 4;
    int h0r = wave * 256;
    f32x4 acc[16] = {};
    const unsigned short* aw = encB + ((size_t)(l0 + col) << 10) + quad * 8;
#pragma unroll
    for (int ht = 0; ht < 16; ++ht) {
      const unsigned short* bw = WcB + ((size_t)(h0r + ht * 16 + col) << 10) + quad * 8;
#pragma unroll 8
      for (int kk = 0; kk < 32; ++kk) {
        bf16x8 a = *(const bf16x8*)(aw + kk * 32);
        bf16x8 b = *(const bf16x8*)(bw + kk * 32);
        acc[ht] = __builtin_amdgcn_mfma_f32_16x16x32_bf16(a, b, acc[ht], 0, 0, 0);
      }
    }
    float rsum[4] = {0.f, 0.f, 0.f, 0.f};
#pragma unroll
    for (int ht = 0; ht < 16; ++ht) {
      int h = h0r + ht * 16 + col;
      float bch = bc[h], hw = hvec[h];
#pragma unroll
      for (int r = 0; r < 4; ++r) rsum[r] += tanhf(acc[ht][r] + bch) * hw;
    }
#pragma unroll
    for (int o = 1; o < 16; o <<= 1)
#pragma unroll
      for (int r = 0; r < 4; ++r) rsum[r] += __shfl_xor(rsum[r], o, 64);
    if (col == 0) {
#pragma unroll
      for (int r = 0; r < 4; ++r) sred[wave][quad * 4 + r] = rsum[r];
    }
    __syncthreads();
    if (tid < 16) {
      float s = sred[0][tid] + sred[1][tid] + sred[2][tid] + sred[3][tid];
      score[VSZ + l0 + tid] = s;
      float e = expf(s - SHIFT);
#pragma unroll
      for (int o = 1; o < 16; o <<= 1) e += __shfl_xor(e, o, 64);
      if (tid == 0) atomicAdd(&psum[((bid * 37) & 63) * 32], e);
    }
  } else {
    __shared__ float xs[HSZ];
    __shared__ float es[4];
    // inline GRU: h_new into LDS (recomputed per block, ~4 KB of ALU)
#pragma unroll
    for (int j = 0; j < 4; ++j) {
      int i = tid + 256 * j;
      float r = 1.f / (1.f + expf(-(gi[i] + gh[i])));
      float z = 1.f / (1.f + expf(-(gi[HSZ + i] + gh[HSZ + i])));
      float n = tanhf(gi[2 * HSZ + i] + r * gh[2 * HSZ + i]);
      float hn = (1.f - z) * n + z * h0[i];
      xs[i] = hn;
      if (bid == NGEMM) { out[VSZ + i] = hn; out[VSZ + HSZ + i] = 0.f; }
    }
    __syncthreads();
    int r0 = (bid - NGEMM) * 8 + wave * 2;
    int ra = r0 < VSZ ? r0 : VSZ - 1;
    int rb = r0 + 1 < VSZ ? r0 + 1 : VSZ - 1;
    const float4* xv = (const float4*)xs;
    float4 x0 = xv[lane], x1 = xv[lane + 64], x2 = xv[lane + 128], x3 = xv[lane + 192];
    const float4* p0 = (const float4*)(Wg + (size_t)ra * HSZ);
    const float4* p1 = (const float4*)(Wg + (size_t)rb * HSZ);
    float4 a0 = p0[lane], a1 = p0[lane + 64], a2 = p0[lane + 128], a3 = p0[lane + 192];
    float4 b0 = p1[lane], b1 = p1[lane + 64], b2 = p1[lane + 128], b3 = p1[lane + 192];
    float s0 = a0.x * x0.x + a0.y * x0.y + a0.z * x0.z + a0.w * x0.w
             + a1.x * x1.x + a1.y * x1.y + a1.z * x1.z + a1.w * x1.w
             + a2.x * x2.x + a2.y * x2.y + a2.z * x2.z + a2.w * x2.w
             + a3.x * x3.x + a3.y * x3.y + a3.z * x3.z + a3.w * x3.w;
    float s1 = b0.x * x0.x + b0.y * x0.y + b0.z * x0.z + b0.w * x0.w
             + b1.x * x1.x + b1.y * x1.y + b1.z * x1.z + b1.w * x1.w
             + b2.x * x2.x + b2.y * x2.y + b2.z * x2.z + b2.w * x2.w
             + b3.x * x3.x + b3.y * x3.y + b3.z * x3.z + b3.w * x3.w;
#pragma unroll
    for (int o = 32; o > 0; o >>= 1) {
      s0 += __shfl_down(s0, o, 64);
      s1 += __shfl_down(s1, o, 64);
    }
    if (lane == 0) {
      float e = 0.f;
      if (r0 < VSZ)     { float v = s0 + bg[r0];     score[r0] = v;     e += expf(v - SHIFT); }
      if (r0 + 1 < VSZ) { float v = s1 + bg[r0 + 1]; score[r0 + 1] = v; e += expf(v - SHIFT); }
      es[wave] = e;
    }
    __syncthreads();
    if (tid == 0)
      atomicAdd(&psum[((bid * 37) & 63) * 32], es[0] + es[1] + es[2] + es[3]);
  }
}

// ============ K6: final probs ============
__global__ void k_final(const float* __restrict__ score, const float* __restrict__ psum,
                        const int* __restrict__ idx, const int* __restrict__ din,
                        const float* __restrict__ enc, float* __restrict__ out) {
  __shared__ float sinv;
  int bid = blockIdx.x, t = threadIdx.x;
  if (t < 64) {
    float v = psum[t * 32];
#pragma unroll
    for (int o = 1; o < 64; o <<= 1) v += __shfl_xor(v, o, 64);
    if (t == 0) sinv = 1.f / v;
  }
  __syncthreads();
  float inv = sinv;
  if (bid < 197) {
    int v = bid * 256 + t;
    if (v < VSZ) atomicAdd(&out[v], expf(score[v] - SHIFT) * inv);
  } else {
    __shared__ float pm[256];
    __shared__ int flag;
    if (t == 0) flag = 0;
    __syncthreads();
    int l0 = (bid - 197) * 256;
    int l = l0 + t;
    float p = expf(score[VSZ + l] - SHIFT) * inv;
    atomicAdd(&out[idx[l]], p);
    int matched = (idx[l] == din[0]);
    pm[t] = matched ? p : 0.f;
    if (matched) atomicExch(&flag, 1);
    __syncthreads();
    if (flag) {
      for (int h = t; h < HSZ; h += 256) {
        float s = 0.f;
        for (int l2 = 0; l2 < 256; ++l2)
          if (pm[l2] != 0.f) s = fmaf(pm[l2], enc[(size_t)(l0 + l2) * HSZ + h], s);
        if (s != 0.f) atomicAdd(&out[VSZ + HSZ + h], s);
      }
    }
  }
}

extern "C" void kernel_launch(void* const* d_in, const int* in_sizes, int n_in,
                              void* d_out, int out_size, void* d_ws, size_t ws_size,
                              hipStream_t stream) {
  const int*   din = (const int*)d_in[0];
  const float* h0  = (const float*)d_in[1];
  const float* enc = (const float*)d_in[2];
  const int*   idx = (const int*)d_in[3];
  const float* emb = (const float*)d_in[4];
  const float* Waw = (const float*)d_in[5];
  const float* baw = (const float*)d_in[6];
  const float* Wau = (const float*)d_in[7];
  const float* bau = (const float*)d_in[8];
  const float* Wih = (const float*)d_in[9];
  const float* bih = (const float*)d_in[10];
  const float* Whh = (const float*)d_in[11];
  const float* bhh = (const float*)d_in[12];
  const float* Wc  = (const float*)d_in[13];
  const float* bc  = (const float*)d_in[14];
  const float* Wg  = (const float*)d_in[15];
  const float* bg  = (const float*)d_in[16];
  float* out = (float*)d_out;
  float* ws  = (float*)d_ws;

  // ws layout (floats), 16B-aligned:
  float* acc    = ws;             // 1024
  float* part   = ws + 1024;      // 1024
  float* rnn_in = ws + 2048;      // 1024
  float* gi     = ws + 3072;      // 3072
  float* gh     = ws + 6144;      // 3072
  float* attnw  = ws + 9216;      // 2048
  float* score  = ws + 11264;     // 52305 (+pad)
  float* psum   = ws + 63616;     // 2048 (64 buckets, stride 32)
  unsigned short* bfbuf = (unsigned short*)(ws + 65664);  // encB 2097152, WcB 1048576 shorts
  unsigned short* encB = bfbuf;
  unsigned short* WcB  = bfbuf + 2097152;

  k_pre<<<2502, 256, 0, stream>>>(Waw, baw, din, emb, h0, enc, Wc, Whh, bhh, Wau, bau,
                                  attnw, gh, part, out, psum, bfbuf);
  k_attn_apply<<<128, 256, 0, stream>>>(attnw, enc, acc);
  k_rnn2<<<256, 256, 0, stream>>>(Wau, part, acc, rnn_in);
  k_gi<<<768, 256, 0, stream>>>(Wih, bih, rnn_in, gi);
  k_huge<<<NGEMM + NGEMV, 256, 0, stream>>>(encB, WcB, bc, h0, Wg, bg, gi, gh, h0,
                                            score, psum, out);
  k_final<<<205, 256, 0, stream>>>(score, psum, idx, din, enc, out);
}